// Round 6
// baseline (491.714 us; speedup 1.0000x reference)
//
#include <hip/hip_runtime.h>

typedef _Float16 f16;
typedef _Float16 f16x8 __attribute__((ext_vector_type(8)));
typedef float f32x4 __attribute__((ext_vector_type(4)));

#define B_   4
#define C_   256
#define N_   4096
#define OUT_ 256

// ---------------------------------------------------------------------------
// Kernel A: transpose+convert x [B,C,N] f32 -> xt [B,N,C] f16, W -> Wt[o][c] f16,
// and zero the BN-stats accumulators (block 1088).
// ---------------------------------------------------------------------------
__global__ __launch_bounds__(256) void k_prep(const float* __restrict__ x,
                                              const float* __restrict__ W,
                                              f16* __restrict__ xt,
                                              f16* __restrict__ Wt,
                                              float* __restrict__ stats) {
    int bid = blockIdx.x;
    int t = threadIdx.x;
    if (bid < 1024) {
        int b  = bid >> 8;
        int ct = (bid >> 6) & 3;
        int nt = bid & 63;
        int c0 = ct * 64, n0 = nt * 64;
        __shared__ float tile[64][65];
        int nl = t & 63;
        int r0 = t >> 6;
        #pragma unroll
        for (int i = 0; i < 16; ++i) {
            int cl = i * 4 + r0;
            tile[cl][nl] = x[((b * C_ + c0 + cl) * N_) + n0 + nl];
        }
        __syncthreads();
        #pragma unroll
        for (int i = 0; i < 16; ++i) {
            int nl2 = i * 4 + r0;
            int cl2 = nl;
            xt[((b * N_ + n0 + nl2) * C_) + c0 + cl2] = (f16)tile[cl2][nl2];
        }
    } else if (bid < 1088) {
        int wb = bid - 1024;
        #pragma unroll
        for (int i = 0; i < 4; ++i) {
            int idx = wb * 1024 + i * 256 + t;
            int c = idx >> 8, o = idx & 255;
            Wt[o * C_ + c] = (f16)W[idx];
        }
    } else {
        if (t < 512) stats[t] = 0.f;
    }
}

// ---------------------------------------------------------------------------
// Kernel B: support^T[b][o][m] = sum_c xt[b][m][c] * W[c][o]   (f16 out)
// ---------------------------------------------------------------------------
__global__ __launch_bounds__(256) void k_support(const f16* __restrict__ xt,
                                                 const f16* __restrict__ Wt,
                                                 f16* __restrict__ supT) {
    int bid = blockIdx.x;
    int b  = bid >> 8;
    int ot = (bid >> 6) & 3;
    int mt = bid & 63;
    int o0 = ot * 64, m0 = mt * 64;
    __shared__ __align__(16) f16 Ws[64][264];
    __shared__ __align__(16) f16 Xs[64][264];
    int t = threadIdx.x;
    int wave = t >> 6, lane = t & 63, q = lane >> 4, l15 = lane & 15;
    #pragma unroll
    for (int p = 0; p < 8; ++p) {
        int idx = p * 256 + t;
        int row = idx >> 5, ch = (idx & 31) * 8;
        *(uint4*)&Ws[row][ch] = *(const uint4*)&Wt[(o0 + row) * C_ + ch];
        *(uint4*)&Xs[row][ch] = *(const uint4*)&xt[((b * N_) + m0 + row) * C_ + ch];
    }
    __syncthreads();
    f32x4 acc[4] = {};
    #pragma unroll
    for (int kk = 0; kk < 8; ++kk) {
        f16x8 a = *(f16x8*)&Ws[16 * wave + l15][kk * 32 + q * 8];
        #pragma unroll
        for (int ct = 0; ct < 4; ++ct) {
            f16x8 bb = *(f16x8*)&Xs[16 * ct + l15][kk * 32 + q * 8];
            acc[ct] = __builtin_amdgcn_mfma_f32_16x16x32_f16(a, bb, acc[ct], 0, 0, 0);
        }
    }
    #pragma unroll
    for (int ct = 0; ct < 4; ++ct)
        #pragma unroll
        for (int r = 0; r < 4; ++r) {
            int og = o0 + 16 * wave + q * 4 + r;
            int mg = m0 + 16 * ct + l15;
            supT[((b * OUT_ + og) * N_) + mg] = (f16)acc[ct][r];
        }
}

// ---------------------------------------------------------------------------
// Kernel C: split-K(2) flash, BN=32 tiles (37 KB LDS -> 4 blocks/CU).
// grid 512: bid = h*256 + b*64 + nb  (consecutive bids share (h,b) -> L2 regime).
// BM=64 (Q in regs), 64 iters over m-range [h*2048,(h+1)*2048).
// Vt/Ps XOR-swizzled (granule ^= row&3), Ks padded.
// ---------------------------------------------------------------------------
__global__ __launch_bounds__(256, 4) void k_flash(const f16* __restrict__ xt,
                                                  const f16* __restrict__ supT,
                                                  f16* __restrict__ Op,
                                                  float* __restrict__ Ml) {
    int bid = blockIdx.x;
    int h  = bid >> 8;
    int b  = (bid >> 6) & 3;
    int n0 = (bid & 63) * 64;

    __shared__ __align__(16) f16 Ks[32][260];   // 16640 B
    __shared__ __align__(16) f16 Vt[256][32];   // 16384 B, swizzled
    __shared__ __align__(16) f16 Ps[64][32];    //  4096 B, swizzled
    __shared__ __align__(16) float Al[64];      //   256 B   (~37.4 KB)

    int t = threadIdx.x;
    int wave = t >> 6, lane = t & 63, q = lane >> 4, l15 = lane & 15;

    // Q fragments: rows 16*wave + l15, 256 channels -> 8 f16x8 (32 VGPRs)
    const f16* qbase = xt + ((size_t)(b * N_) + n0 + 16 * wave + l15) * C_;
    f16x8 qf[8];
    #pragma unroll
    for (int kk = 0; kk < 8; ++kk)
        qf[kk] = *(const f16x8*)&qbase[kk * 32 + q * 8];

    f32x4 oacc[4][4] = {};
    float m_run[4], l_run[4];
    #pragma unroll
    for (int r = 0; r < 4; ++r) { m_run[r] = -1e30f; l_run[r] = 0.f; }

    for (int it = 0; it < 64; ++it) {
        int m0 = h * 2048 + it * 32;
        // stage K (32 x 256): 4 uint4/thread
        #pragma unroll
        for (int p = 0; p < 4; ++p) {
            int idx = p * 256 + t;
            int row = idx >> 5, ch = (idx & 31) * 8;
            *(uint4*)&Ks[row][ch] = *(const uint4*)&xt[((b * N_) + m0 + row) * C_ + ch];
        }
        // stage V^T (256 x 32), granule-swizzled
        #pragma unroll
        for (int p = 0; p < 4; ++p) {
            int idx = p * 256 + t;
            int o = idx >> 2, g = idx & 3;
            *(uint4*)&Vt[o][(g ^ (o & 3)) * 8] =
                *(const uint4*)&supT[((b * OUT_ + o) * N_) + m0 + g * 8];
        }
        __syncthreads();

        // S = Q K^T (64x32, K=256); wave owns rows 16*wave..+15
        f32x4 sacc[2] = {};
        #pragma unroll
        for (int kk = 0; kk < 8; ++kk) {
            #pragma unroll
            for (int ct = 0; ct < 2; ++ct) {
                f16x8 bb = *(f16x8*)&Ks[16 * ct + l15][kk * 32 + q * 8];
                sacc[ct] = __builtin_amdgcn_mfma_f32_16x16x32_f16(qf[kk], bb, sacc[ct], 0, 0, 0);
            }
        }
        // online softmax; publish P (swizzled f16) and alpha
        float alpha[4];
        #pragma unroll
        for (int r = 0; r < 4; ++r) {
            float mx = fmaxf(sacc[0][r], sacc[1][r]);
            mx = fmaxf(mx, __shfl_xor(mx, 1));
            mx = fmaxf(mx, __shfl_xor(mx, 2));
            mx = fmaxf(mx, __shfl_xor(mx, 4));
            mx = fmaxf(mx, __shfl_xor(mx, 8));
            float mnew = fmaxf(m_run[r], mx);
            alpha[r] = __expf(m_run[r] - mnew);
            m_run[r] = mnew;
            float p0 = __expf(sacc[0][r] - mnew);
            float p1 = __expf(sacc[1][r] - mnew);
            float sum = p0 + p1;
            sum += __shfl_xor(sum, 1);
            sum += __shfl_xor(sum, 2);
            sum += __shfl_xor(sum, 4);
            sum += __shfl_xor(sum, 8);
            l_run[r] = l_run[r] * alpha[r] + sum;
            int row = 16 * wave + q * 4 + r;
            int sw = (r & 3);  // row & 3
            int gi0 = (0 * 2 + (l15 >> 3)) ^ sw;
            int gi1 = (1 * 2 + (l15 >> 3)) ^ sw;
            Ps[row][gi0 * 8 + (l15 & 7)] = (f16)p0;
            Ps[row][gi1 * 8 + (l15 & 7)] = (f16)p1;
            if (l15 == 0) Al[row] = alpha[r];
        }
        __syncthreads();

        // rescale O by alpha, then O += P V; wave owns o-slab [64*wave, +64)
        float4 av[4];
        #pragma unroll
        for (int nt = 0; nt < 4; ++nt)
            av[nt] = *(const float4*)&Al[16 * nt + 4 * q];
        #pragma unroll
        for (int nt = 0; nt < 4; ++nt)
            #pragma unroll
            for (int ot = 0; ot < 4; ++ot)
                #pragma unroll
                for (int r = 0; r < 4; ++r)
                    oacc[nt][ot][r] *= ((const float*)&av[nt])[r];
        {
            f16x8 af[4], bf[4];
            #pragma unroll
            for (int nt = 0; nt < 4; ++nt) {
                int prow = 16 * nt + l15;
                af[nt] = *(f16x8*)&Ps[prow][(q ^ (prow & 3)) * 8];
            }
            #pragma unroll
            for (int ot = 0; ot < 4; ++ot) {
                int orow = 64 * wave + 16 * ot + l15;
                bf[ot] = *(f16x8*)&Vt[orow][(q ^ (orow & 3)) * 8];
            }
            #pragma unroll
            for (int nt = 0; nt < 4; ++nt)
                #pragma unroll
                for (int ot = 0; ot < 4; ++ot)
                    oacc[nt][ot] = __builtin_amdgcn_mfma_f32_16x16x32_f16(af[nt], bf[ot], oacc[nt][ot], 0, 0, 0);
        }
        __syncthreads();
    }

    // store l-normalized f16 partials + (m,l)
    if (l15 == 0) {
        #pragma unroll
        for (int r = 0; r < 4; ++r)
            Al[16 * wave + q * 4 + r] = 1.0f / l_run[r];
    }
    __syncthreads();
    float4 lv[4];
    #pragma unroll
    for (int nt = 0; nt < 4; ++nt)
        lv[nt] = *(const float4*)&Al[16 * nt + 4 * q];

    f16* Obase = Op + (size_t)bid * (64 * 256);
    #pragma unroll
    for (int nt = 0; nt < 4; ++nt)
        #pragma unroll
        for (int ot = 0; ot < 4; ++ot)
            #pragma unroll
            for (int r = 0; r < 4; ++r) {
                int n = 16 * nt + q * 4 + r;
                int o = 64 * wave + 16 * ot + l15;
                Obase[n * 256 + o] = (f16)(oacc[nt][ot][r] * ((const float*)&lv[nt])[r]);
            }
    float* Mlb = Ml + (size_t)bid * 128;
    if (l15 == 0) {
        #pragma unroll
        for (int r = 0; r < 4; ++r) {
            Mlb[16 * wave + q * 4 + r] = m_run[r];
            Mlb[64 + 16 * wave + q * 4 + r] = l_run[r];
        }
    }
}

// ---------------------------------------------------------------------------
// Kernel C2: merge 2 split-K halves + LeakyReLU -> y (f16, [b][o][n]),
// and accumulate per-channel BN sums via atomics.
// ---------------------------------------------------------------------------
__global__ __launch_bounds__(256) void k_merge(const f16* __restrict__ Op,
                                               const float* __restrict__ Ml,
                                               f16* __restrict__ y,
                                               float* __restrict__ stats) {
    int bid = blockIdx.x;
    int b  = bid >> 6;
    int nb = bid & 63;
    int t = threadIdx.x;
    const f16* O0 = Op + (size_t)bid * (64 * 256);
    const f16* O1 = Op + (size_t)(bid + 256) * (64 * 256);
    __shared__ float cs[2][64];
    if (t < 64) {
        const float* M0 = Ml + (size_t)bid * 128;
        const float* M1 = Ml + (size_t)(bid + 256) * 128;
        float m0 = M0[t], l0 = M0[64 + t];
        float m1 = M1[t], l1 = M1[64 + t];
        float M = fmaxf(m0, m1);
        float w0 = __expf(m0 - M) * l0;
        float w1 = __expf(m1 - M) * l1;
        float inv = 1.0f / (w0 + w1);
        cs[0][t] = w0 * inv;
        cs[1][t] = w1 * inv;
    }
    __syncthreads();
    float vv[64];
    float s = 0.f, ss = 0.f;
    #pragma unroll
    for (int n = 0; n < 64; ++n) {
        float v = cs[0][n] * (float)O0[n * 256 + t] + cs[1][n] * (float)O1[n * 256 + t];
        v = v >= 0.f ? v : 0.01f * v;
        vv[n] = v;
        s += v;
        ss += v * v;
    }
    f16* dst = y + ((size_t)(b * OUT_ + t)) * N_ + nb * 64;
    #pragma unroll
    for (int c = 0; c < 8; ++c) {
        f16x8 w;
        #pragma unroll
        for (int j = 0; j < 8; ++j) w[j] = (f16)vv[8 * c + j];
        *(f16x8*)&dst[8 * c] = w;
    }
    atomicAdd(&stats[t], s);
    atomicAdd(&stats[256 + t], ss);
}

// ---------------------------------------------------------------------------
// Kernel E: out = gamma*(y-mean)*rstd + beta, f16 y -> f32 out.
// ---------------------------------------------------------------------------
__global__ __launch_bounds__(256) void k_bnapply(const f16* __restrict__ y,
                                                 const float* __restrict__ stats,
                                                 const float* __restrict__ gamma,
                                                 const float* __restrict__ beta,
                                                 float* __restrict__ out) {
    int b = blockIdx.x >> 8;
    int o = blockIdx.x & 255;
    int t = threadIdx.x;
    float mean = stats[o] * (1.0f / 16384.0f);
    float var = stats[256 + o] * (1.0f / 16384.0f) - mean * mean;
    float rstd = rsqrtf(var + 1e-5f);
    float g = gamma[o] * rstd;
    float bt = beta[o] - mean * g;
    const f16* src = y + ((size_t)(b * OUT_ + o)) * N_ + t * 16;
    float* dst = out + ((size_t)(b * OUT_ + o)) * N_ + t * 16;
    #pragma unroll
    for (int i = 0; i < 2; ++i) {
        f16x8 v = *(const f16x8*)&src[i * 8];
        float4 a, c;
        a.x = (float)v[0] * g + bt;
        a.y = (float)v[1] * g + bt;
        a.z = (float)v[2] * g + bt;
        a.w = (float)v[3] * g + bt;
        c.x = (float)v[4] * g + bt;
        c.y = (float)v[5] * g + bt;
        c.z = (float)v[6] * g + bt;
        c.w = (float)v[7] * g + bt;
        *(float4*)&dst[i * 8] = a;
        *(float4*)&dst[i * 8 + 4] = c;
    }
}

extern "C" void kernel_launch(void* const* d_in, const int* in_sizes, int n_in,
                              void* d_out, int out_size, void* d_ws, size_t ws_size,
                              hipStream_t stream) {
    const float* x     = (const float*)d_in[0];
    const float* W     = (const float*)d_in[1];
    const float* gamma = (const float*)d_in[2];
    const float* beta  = (const float*)d_in[3];
    float* out = (float*)d_out;

    f16* xt    = (f16*)d_ws;                      // 8 MB (reused as y by merge)
    f16* supT  = xt + (size_t)B_ * N_ * C_;       // 8 MB
    f16* Wt    = supT + (size_t)B_ * N_ * OUT_;   // 128 KB
    f16* Op    = Wt + C_ * OUT_;                  // 512*32KB = 16.8 MB
    float* Ml  = (float*)(Op + (size_t)512 * 64 * 256);  // 256 KB
    float* stats = Ml + 512 * 128;                // 2 KB
    f16* y     = xt;                              // alias: xt dead after flash

    k_prep<<<1089, 256, 0, stream>>>(x, W, xt, Wt, stats);
    k_support<<<1024, 256, 0, stream>>>(xt, Wt, supT);
    k_flash<<<512, 256, 0, stream>>>(xt, supT, Op, Ml);
    k_merge<<<256, 256, 0, stream>>>(Op, Ml, y, stats);
    k_bnapply<<<1024, 256, 0, stream>>>(y, stats, gamma, beta, out);
}

// Round 7
// 329.276 us; speedup vs baseline: 1.4933x; 1.4933x over previous
//
#include <hip/hip_runtime.h>

typedef _Float16 f16;
typedef _Float16 f16x8 __attribute__((ext_vector_type(8)));
typedef float f32x4 __attribute__((ext_vector_type(4)));

#define B_   4
#define C_   256
#define N_   4096
#define OUT_ 256

// ---------------------------------------------------------------------------
// Kernel A: transpose+convert x [B,C,N] f32 -> xt [B,N,C] f16, W -> Wt[o][c] f16,
// and zero the BN-stats accumulators (block 1088).
// ---------------------------------------------------------------------------
__global__ __launch_bounds__(256) void k_prep(const float* __restrict__ x,
                                              const float* __restrict__ W,
                                              f16* __restrict__ xt,
                                              f16* __restrict__ Wt,
                                              float* __restrict__ stats) {
    int bid = blockIdx.x;
    int t = threadIdx.x;
    if (bid < 1024) {
        int b  = bid >> 8;
        int ct = (bid >> 6) & 3;
        int nt = bid & 63;
        int c0 = ct * 64, n0 = nt * 64;
        __shared__ float tile[64][65];
        int nl = t & 63;
        int r0 = t >> 6;
        #pragma unroll
        for (int i = 0; i < 16; ++i) {
            int cl = i * 4 + r0;
            tile[cl][nl] = x[((b * C_ + c0 + cl) * N_) + n0 + nl];
        }
        __syncthreads();
        #pragma unroll
        for (int i = 0; i < 16; ++i) {
            int nl2 = i * 4 + r0;
            int cl2 = nl;
            xt[((b * N_ + n0 + nl2) * C_) + c0 + cl2] = (f16)tile[cl2][nl2];
        }
    } else if (bid < 1088) {
        int wb = bid - 1024;
        #pragma unroll
        for (int i = 0; i < 4; ++i) {
            int idx = wb * 1024 + i * 256 + t;
            int c = idx >> 8, o = idx & 255;
            Wt[o * C_ + c] = (f16)W[idx];
        }
    } else {
        if (t < 512) stats[t] = 0.f;
    }
}

// ---------------------------------------------------------------------------
// Kernel B: support^T[b][o][m] = sum_c xt[b][m][c] * W[c][o]   (f16 out)
// ---------------------------------------------------------------------------
__global__ __launch_bounds__(256) void k_support(const f16* __restrict__ xt,
                                                 const f16* __restrict__ Wt,
                                                 f16* __restrict__ supT) {
    int bid = blockIdx.x;
    int b  = bid >> 8;
    int ot = (bid >> 6) & 3;
    int mt = bid & 63;
    int o0 = ot * 64, m0 = mt * 64;
    __shared__ __align__(16) f16 Ws[64][264];
    __shared__ __align__(16) f16 Xs[64][264];
    int t = threadIdx.x;
    int wave = t >> 6, lane = t & 63, q = lane >> 4, l15 = lane & 15;
    #pragma unroll
    for (int p = 0; p < 8; ++p) {
        int idx = p * 256 + t;
        int row = idx >> 5, ch = (idx & 31) * 8;
        *(uint4*)&Ws[row][ch] = *(const uint4*)&Wt[(o0 + row) * C_ + ch];
        *(uint4*)&Xs[row][ch] = *(const uint4*)&xt[((b * N_) + m0 + row) * C_ + ch];
    }
    __syncthreads();
    f32x4 acc[4] = {};
    #pragma unroll
    for (int kk = 0; kk < 8; ++kk) {
        f16x8 a = *(f16x8*)&Ws[16 * wave + l15][kk * 32 + q * 8];
        #pragma unroll
        for (int ct = 0; ct < 4; ++ct) {
            f16x8 bb = *(f16x8*)&Xs[16 * ct + l15][kk * 32 + q * 8];
            acc[ct] = __builtin_amdgcn_mfma_f32_16x16x32_f16(a, bb, acc[ct], 0, 0, 0);
        }
    }
    #pragma unroll
    for (int ct = 0; ct < 4; ++ct)
        #pragma unroll
        for (int r = 0; r < 4; ++r) {
            int og = o0 + 16 * wave + q * 4 + r;
            int mg = m0 + 16 * ct + l15;
            supT[((b * OUT_ + og) * N_) + mg] = (f16)acc[ct][r];
        }
}

// ---------------------------------------------------------------------------
// Kernel C: split-K(4) flash, XCD-pinned batch, V direct-from-global.
// grid 1024: bid = j*8 + x;  x(=bid&7) -> XCD (round-robin assumption);
//   b = x>>1 (each XCD serves ONE batch -> xt[b]+supT[b] = 4MB = its L2),
//   h = j>>5 (m-quarter), nb = (j&31)*2 + (x&1).
// BM=64 (Q in regs), BN=64, 16 iters over m in [h*1024,(h+1)*1024).
// LDS: Ks (staged, 4x cross-wave reuse) + Ps + Al = 43.3 KB -> 3 blocks/CU.
// V has zero cross-wave reuse -> per-lane global b-frag gathers
// (16 rows x 64B contiguous per instr). 2 barriers/iter.
// ---------------------------------------------------------------------------
__global__ __launch_bounds__(256, 3) void k_flash(const f16* __restrict__ xt,
                                                  const f16* __restrict__ supT,
                                                  f16* __restrict__ Op,
                                                  float* __restrict__ Ml) {
    int bid = blockIdx.x;
    int x8 = bid & 7;
    int j  = bid >> 3;
    int b  = x8 >> 1;
    int h  = j >> 5;
    int nb = ((j & 31) << 1) | (x8 & 1);
    int n0 = nb * 64;

    __shared__ __align__(16) f16 Ks[64][264];   // 33792 B
    __shared__ __align__(16) f16 Ps[64][72];    //  9216 B
    __shared__ __align__(16) float Al[64];      //   256 B  (43264 B total)

    int t = threadIdx.x;
    int wave = t >> 6, lane = t & 63, q = lane >> 4, l15 = lane & 15;

    // Q fragments: rows n0 + 16*wave + l15, 256 channels -> 8 f16x8 (32 VGPRs)
    const f16* qbase = xt + ((size_t)(b * N_) + n0 + 16 * wave + l15) * C_;
    f16x8 qf[8];
    #pragma unroll
    for (int kk = 0; kk < 8; ++kk)
        qf[kk] = *(const f16x8*)&qbase[kk * 32 + q * 8];

    // V gather base: row o = 64*wave + 16*ot + l15, k-offset q*8
    const f16* vb0 = supT + ((size_t)(b * OUT_) + 64 * wave + l15) * N_ + q * 8;

    f32x4 oacc[4][4] = {};
    float m_run[4], l_run[4];
    #pragma unroll
    for (int r = 0; r < 4; ++r) { m_run[r] = -1e30f; l_run[r] = 0.f; }

    for (int it = 0; it < 16; ++it) {
        int m0 = h * 1024 + it * 64;
        // stage K (64 x 256), 8 uint4/thread
        #pragma unroll
        for (int p = 0; p < 8; ++p) {
            int idx = p * 256 + t;
            int row = idx >> 5, ch = (idx & 31) * 8;
            *(uint4*)&Ks[row][ch] = *(const uint4*)&xt[((b * N_) + m0 + row) * C_ + ch];
        }
        __syncthreads();   // (A) staging visible; also guards prev-iter Ps/Al reads

        // S = Q K^T (64x64, K=256); wave owns n-rows 16*wave..+15
        f32x4 sacc[4] = {};
        #pragma unroll
        for (int kk = 0; kk < 8; ++kk) {
            #pragma unroll
            for (int ct = 0; ct < 4; ++ct) {
                f16x8 bb = *(f16x8*)&Ks[16 * ct + l15][kk * 32 + q * 8];
                sacc[ct] = __builtin_amdgcn_mfma_f32_16x16x32_f16(qf[kk], bb, sacc[ct], 0, 0, 0);
            }
        }
        // online softmax; publish P (f16) and alpha
        float alpha[4];
        #pragma unroll
        for (int r = 0; r < 4; ++r) {
            float mx = fmaxf(fmaxf(sacc[0][r], sacc[1][r]), fmaxf(sacc[2][r], sacc[3][r]));
            mx = fmaxf(mx, __shfl_xor(mx, 1));
            mx = fmaxf(mx, __shfl_xor(mx, 2));
            mx = fmaxf(mx, __shfl_xor(mx, 4));
            mx = fmaxf(mx, __shfl_xor(mx, 8));
            float mnew = fmaxf(m_run[r], mx);
            alpha[r] = __expf(m_run[r] - mnew);
            m_run[r] = mnew;
            float p0 = __expf(sacc[0][r] - mnew);
            float p1 = __expf(sacc[1][r] - mnew);
            float p2 = __expf(sacc[2][r] - mnew);
            float p3 = __expf(sacc[3][r] - mnew);
            float sum = p0 + p1 + p2 + p3;
            sum += __shfl_xor(sum, 1);
            sum += __shfl_xor(sum, 2);
            sum += __shfl_xor(sum, 4);
            sum += __shfl_xor(sum, 8);
            l_run[r] = l_run[r] * alpha[r] + sum;
            int row = 16 * wave + q * 4 + r;
            Ps[row][0 * 16 + l15] = (f16)p0;
            Ps[row][1 * 16 + l15] = (f16)p1;
            Ps[row][2 * 16 + l15] = (f16)p2;
            Ps[row][3 * 16 + l15] = (f16)p3;
            if (l15 == 0) Al[row] = alpha[r];
        }
        // V b-frags direct from global (L2-resident), issued before the barrier
        const f16* vb = vb0 + m0;
        f16x8 bf[2][4];
        #pragma unroll
        for (int ks = 0; ks < 2; ++ks)
            #pragma unroll
            for (int ot = 0; ot < 4; ++ot)
                bf[ks][ot] = *(const f16x8*)&vb[(size_t)ot * 16 * N_ + ks * 32];
        __syncthreads();   // (C) Ps/Al visible

        // rescale O by alpha (broadcast via LDS), then O += P V
        float4 av[4];
        #pragma unroll
        for (int nt = 0; nt < 4; ++nt)
            av[nt] = *(const float4*)&Al[16 * nt + 4 * q];
        #pragma unroll
        for (int nt = 0; nt < 4; ++nt)
            #pragma unroll
            for (int ot = 0; ot < 4; ++ot)
                #pragma unroll
                for (int r = 0; r < 4; ++r)
                    oacc[nt][ot][r] *= ((const float*)&av[nt])[r];
        #pragma unroll
        for (int ks = 0; ks < 2; ++ks) {
            #pragma unroll
            for (int nt = 0; nt < 4; ++nt) {
                f16x8 af = *(f16x8*)&Ps[16 * nt + l15][ks * 32 + q * 8];
                #pragma unroll
                for (int ot = 0; ot < 4; ++ot)
                    oacc[nt][ot] = __builtin_amdgcn_mfma_f32_16x16x32_f16(af, bf[ks][ot], oacc[nt][ot], 0, 0, 0);
            }
        }
        // no (D) barrier: next staging writes only Ks (dead after QK, which all
        // waves completed before (C)); next Ps/Al writes are fenced by next (A).
    }

    // store l-normalized f16 partials + (m,l)
    __syncthreads();
    if (l15 == 0) {
        #pragma unroll
        for (int r = 0; r < 4; ++r)
            Al[16 * wave + q * 4 + r] = 1.0f / l_run[r];
    }
    __syncthreads();
    float4 lv[4];
    #pragma unroll
    for (int nt = 0; nt < 4; ++nt)
        lv[nt] = *(const float4*)&Al[16 * nt + 4 * q];

    f16* Obase = Op + (size_t)bid * (64 * 256);
    #pragma unroll
    for (int nt = 0; nt < 4; ++nt)
        #pragma unroll
        for (int ot = 0; ot < 4; ++ot)
            #pragma unroll
            for (int r = 0; r < 4; ++r) {
                int n = 16 * nt + q * 4 + r;
                int o = 64 * wave + 16 * ot + l15;
                Obase[n * 256 + o] = (f16)(oacc[nt][ot][r] * ((const float*)&lv[nt])[r]);
            }
    float* Mlb = Ml + (size_t)bid * 128;
    if (l15 == 0) {
        #pragma unroll
        for (int r = 0; r < 4; ++r) {
            Mlb[16 * wave + q * 4 + r] = m_run[r];
            Mlb[64 + 16 * wave + q * 4 + r] = l_run[r];
        }
    }
}

// ---------------------------------------------------------------------------
// Kernel C2: merge 4 split-K quarters + LeakyReLU -> y (f16, [b][o][n]),
// and accumulate per-channel BN sums via atomics.
// grid 256 = (b, nb); thread t owns output channel o = t.
// flash bid for (b,h,nb) = (h*32 + (nb>>1))*8 + 2*b + (nb&1)
// ---------------------------------------------------------------------------
__global__ __launch_bounds__(256) void k_merge(const f16* __restrict__ Op,
                                               const float* __restrict__ Ml,
                                               f16* __restrict__ y,
                                               float* __restrict__ stats) {
    int bid = blockIdx.x;
    int b  = bid >> 6;
    int nb = bid & 63;
    int t = threadIdx.x;
    int pidx[4];
    #pragma unroll
    for (int h = 0; h < 4; ++h)
        pidx[h] = ((h * 32 + (nb >> 1)) << 3) | (2 * b + (nb & 1));
    const f16* O0 = Op + (size_t)pidx[0] * (64 * 256);
    const f16* O1 = Op + (size_t)pidx[1] * (64 * 256);
    const f16* O2 = Op + (size_t)pidx[2] * (64 * 256);
    const f16* O3 = Op + (size_t)pidx[3] * (64 * 256);
    __shared__ float cs[4][64];
    if (t < 64) {
        float m[4], l[4];
        #pragma unroll
        for (int h = 0; h < 4; ++h) {
            const float* M = Ml + (size_t)pidx[h] * 128;
            m[h] = M[t];
            l[h] = M[64 + t];
        }
        float M = fmaxf(fmaxf(m[0], m[1]), fmaxf(m[2], m[3]));
        float w0 = __expf(m[0] - M) * l[0];
        float w1 = __expf(m[1] - M) * l[1];
        float w2 = __expf(m[2] - M) * l[2];
        float w3 = __expf(m[3] - M) * l[3];
        float inv = 1.0f / (w0 + w1 + w2 + w3);
        cs[0][t] = w0 * inv;
        cs[1][t] = w1 * inv;
        cs[2][t] = w2 * inv;
        cs[3][t] = w3 * inv;
    }
    __syncthreads();
    float vv[64];
    float s = 0.f, ss = 0.f;
    #pragma unroll
    for (int n = 0; n < 64; ++n) {
        float v = cs[0][n] * (float)O0[n * 256 + t] + cs[1][n] * (float)O1[n * 256 + t] +
                  cs[2][n] * (float)O2[n * 256 + t] + cs[3][n] * (float)O3[n * 256 + t];
        v = v >= 0.f ? v : 0.01f * v;
        vv[n] = v;
        s += v;
        ss += v * v;
    }
    f16* dst = y + ((size_t)(b * OUT_ + t)) * N_ + nb * 64;
    #pragma unroll
    for (int c = 0; c < 8; ++c) {
        f16x8 w;
        #pragma unroll
        for (int j = 0; j < 8; ++j) w[j] = (f16)vv[8 * c + j];
        *(f16x8*)&dst[8 * c] = w;
    }
    atomicAdd(&stats[t], s);
    atomicAdd(&stats[256 + t], ss);
}

// ---------------------------------------------------------------------------
// Kernel E: out = gamma*(y-mean)*rstd + beta, f16 y -> f32 out.
// ---------------------------------------------------------------------------
__global__ __launch_bounds__(256) void k_bnapply(const f16* __restrict__ y,
                                                 const float* __restrict__ stats,
                                                 const float* __restrict__ gamma,
                                                 const float* __restrict__ beta,
                                                 float* __restrict__ out) {
    int b = blockIdx.x >> 8;
    int o = blockIdx.x & 255;
    int t = threadIdx.x;
    float mean = stats[o] * (1.0f / 16384.0f);
    float var = stats[256 + o] * (1.0f / 16384.0f) - mean * mean;
    float rstd = rsqrtf(var + 1e-5f);
    float g = gamma[o] * rstd;
    float bt = beta[o] - mean * g;
    const f16* src = y + ((size_t)(b * OUT_ + o)) * N_ + t * 16;
    float* dst = out + ((size_t)(b * OUT_ + o)) * N_ + t * 16;
    #pragma unroll
    for (int i = 0; i < 2; ++i) {
        f16x8 v = *(const f16x8*)&src[i * 8];
        float4 a, c;
        a.x = (float)v[0] * g + bt;
        a.y = (float)v[1] * g + bt;
        a.z = (float)v[2] * g + bt;
        a.w = (float)v[3] * g + bt;
        c.x = (float)v[4] * g + bt;
        c.y = (float)v[5] * g + bt;
        c.z = (float)v[6] * g + bt;
        c.w = (float)v[7] * g + bt;
        *(float4*)&dst[i * 8] = a;
        *(float4*)&dst[i * 8 + 4] = c;
    }
}

extern "C" void kernel_launch(void* const* d_in, const int* in_sizes, int n_in,
                              void* d_out, int out_size, void* d_ws, size_t ws_size,
                              hipStream_t stream) {
    const float* x     = (const float*)d_in[0];
    const float* W     = (const float*)d_in[1];
    const float* gamma = (const float*)d_in[2];
    const float* beta  = (const float*)d_in[3];
    float* out = (float*)d_out;

    f16* xt    = (f16*)d_ws;                      // 8 MB (reused as y by merge)
    f16* supT  = xt + (size_t)B_ * N_ * C_;       // 8 MB
    f16* Wt    = supT + (size_t)B_ * N_ * OUT_;   // 128 KB
    f16* Op    = Wt + C_ * OUT_;                  // 1024*32KB = 33.6 MB
    float* Ml  = (float*)(Op + (size_t)1024 * 64 * 256);  // 512 KB
    float* stats = Ml + 1024 * 128;               // 2 KB
    f16* y     = xt;                              // alias: xt dead after flash

    k_prep<<<1089, 256, 0, stream>>>(x, W, xt, Wt, stats);
    k_support<<<1024, 256, 0, stream>>>(xt, Wt, supT);
    k_flash<<<1024, 256, 0, stream>>>(xt, supT, Op, Ml);
    k_merge<<<256, 256, 0, stream>>>(Op, Ml, y, stats);
    k_bnapply<<<1024, 256, 0, stream>>>(y, stats, gamma, beta, out);
}